// Round 4
// baseline (152.198 us; speedup 1.0000x reference)
//
#include <hip/hip_runtime.h>
#include <math.h>

// ---- workspace layout (float offsets); ws_size ~268 MB, we use ~19 MB ----
#define WS_MAP      0            // 524288: B x 256 x 256 raw map
#define WS_PART     524288       // 128 chunks x 8192 x float4 partials (16 MB)
#define WS_POS4     4718592      // 10240 x float4 (x,y,z,pol), padded
#define WS_ECC      4759552      // 10240 ecc, padded
#define WS_EPOS     4769792      // 8192 x float4 (px,py,pz,prob)
#define WS_PAR4     4802560      // 8192 x float4 (cx,cy,1/(s^2+eps),w)
#define WS_MAX      4835328      // 8 per-b max

#define NB 8
#define NN 1000
#define NV 10000
#define NV2 10240                // padded V (128 chunks x 80)
#define NE 8192                  // padded electrodes
#define NCHUNK 128
#define CHUNK 80

// Fused: per-batch setup (redundant per block, trivial) + v1 packing + electrode
// positions + sigmoid(logit). 40 blocks x 256 = 10240 threads.
__global__ __launch_bounds__(256) void k_packepos(const float* __restrict__ v1_pos,
                                                  const float* __restrict__ v1_prf,
                                                  const float* __restrict__ logits,
                                                  const float* __restrict__ tmpl,
                                                  const float* __restrict__ params,
                                                  const float* __restrict__ start_loc,
                                                  const float* __restrict__ lut,
                                                  const float* __restrict__ agrid,
                                                  const float* __restrict__ bgrid,
                                                  float* __restrict__ ws) {
    __shared__ float st[NB][13];
    int t = blockIdx.x*256 + threadIdx.x;
    if (threadIdx.x < NB) {
        int b = threadIdx.x;
        float alpha = params[b*4+0], beta = params[b*4+1];
        float off   = params[b*4+2], shank = params[b*4+3];
        const float D2R = 0.017453292519943295f;
        float a = alpha*D2R, bb = beta*D2R;
        float ca = cosf(a), sa = sinf(a), cb = cosf(bb), sb = sinf(bb);
        // R = Rx(alpha) @ Ry(beta)
        float r00=cb,     r01=0.f, r02=sb;
        float r10=sa*sb,  r11=ca,  r12=-sa*cb;
        float r20=-ca*sb, r21=sa,  r22=ca*cb;
        // direction = normalize(R @ (0,0,-1)) = -col2
        float dx=-r02, dy=-r12, dz=-r22;
        float inv = rsqrtf(dx*dx+dy*dy+dz*dz);
        dx*=inv; dy*=inv; dz*=inv;
        // bilinear interp of 37x26 LUT, matching reference arithmetic
        float ag0=agrid[0], agN=agrid[36], bg0=bgrid[0], bgN=bgrid[25];
        float an = 2.f*(alpha-ag0)/(agN-ag0+1e-8f) - 1.f;
        float bn = 2.f*(beta -bg0)/(bgN-bg0+1e-8f) - 1.f;
        float ai = fminf(fmaxf((an+1.f)*0.5f*36.f, 0.f), 36.f);
        float bi = fminf(fmaxf((bn+1.f)*0.5f*25.f, 0.f), 25.f);
        int a0 = (int)floorf(ai); a0 = a0<0?0:(a0>36?36:a0);
        int b0 = (int)floorf(bi); b0 = b0<0?0:(b0>25?25:b0);
        int a1 = a0+1>36?36:a0+1;
        int b1 = b0+1>25?25:b0+1;
        float fa = ai - (float)a0, fb = bi - (float)b0;
        float v00=lut[a0*26+b0], v01=lut[a0*26+b1], v10=lut[a1*26+b0], v11=lut[a1*26+b1];
        float sd = v00*(1.f-fa)*(1.f-fb) + v01*(1.f-fa)*fb + v10*fa*(1.f-fb) + v11*fa*fb;
        sd = fmaxf(sd, 1.f);
        float pen = sd - shank*0.5f - off;
        st[b][0]=r00; st[b][1]=r01; st[b][2]=r02;
        st[b][3]=r10; st[b][4]=r11; st[b][5]=r12;
        st[b][6]=r20; st[b][7]=r21; st[b][8]=r22;
        st[b][9]  = start_loc[0] + dx*pen;
        st[b][10] = start_loc[1] + dy*pen;
        st[b][11] = start_loc[2] + dz*pen;
        st[b][12] = shank;
    }
    __syncthreads();
    // pack v1 (pad to NV2 with far-away points -> wv == 0 exactly)
    {
        float4* p4 = (float4*)(ws + WS_POS4);
        if (t < NV) {
            p4[t] = make_float4(v1_pos[t*3+0], v1_pos[t*3+1], v1_pos[t*3+2], v1_prf[t*3+0]);
            ws[WS_ECC + t] = v1_prf[t*3+1];
        } else {   // t in [NV, NV2)
            p4[t] = make_float4(1e9f, 1e9f, 1e9f, 0.f);
            ws[WS_ECC + t] = 0.f;
        }
    }
    if (t < NE) {
        float4* ep = (float4*)(ws + WS_EPOS);
        if (t < NB*NN) {
            int b = t / NN, n = t % NN;
            // centered grid point (template means are analytically 1.8, 1.8, 0.5)
            float gx = tmpl[n*3+0]-1.8f, gy = tmpl[n*3+1]-1.8f;
            float gz = (tmpl[n*3+2]-0.5f)*st[b][12];
            float px = st[b][0]*gx + st[b][1]*gy + st[b][2]*gz + st[b][9];
            float py = st[b][3]*gx + st[b][4]*gy + st[b][5]*gz + st[b][10];
            float pz = st[b][6]*gx + st[b][7]*gy + st[b][8]*gz + st[b][11];
            float prob = 1.f/(1.f + __expf(-logits[t]));
            ep[t] = make_float4(px, py, pz, prob);
        } else {
            ep[t] = make_float4(1e9f, 1e9f, 1e9f, 0.f);
        }
    }
}

// LDS-staged soft-match, 2 electrodes per thread.
// 2048 blocks = 128 V-chunks x 16 electrode groups -> 8 blocks/CU (100% occupancy;
// launch_bounds(256,8) caps VGPR at 64 to guarantee residency).
__global__ __launch_bounds__(256, 8) void k_weights(float* __restrict__ ws) {
    __shared__ float4 sq[CHUNK];
    __shared__ float  sec[CHUNK];
    int g  = blockIdx.x;
    int c  = g >> 4;                 // chunk 0..127
    int eg = g & 15;                 // electrode group 0..15 (512 each)
    int t  = threadIdx.x;
    int v0 = c*CHUNK;
    if (t < CHUNK) {
        sq[t]  = ((const float4*)(ws + WS_POS4))[v0 + t];
        sec[t] = ws[WS_ECC + v0 + t];
    }
    __syncthreads();
    const float4* ep = (const float4*)(ws + WS_EPOS);
    int e0 = eg*512 + t;
    float4 P0 = ep[e0], P1 = ep[e0+256];
    float sw0=0,sp0=0,se0=0, sw1=0,sp1=0,se1=0;
    const float C = -0.32059889797532524f;   // -(1/4.5)*log2(e): exp2 -> v_exp_f32
    #pragma unroll 4
    for (int i = 0; i < CHUNK; ++i) {
        float4 q = sq[i];
        float ecc = sec[i];
        { float dx=P0.x-q.x, dy=P0.y-q.y, dz=P0.z-q.z;
          float wv = exp2f((dx*dx+dy*dy+dz*dz)*C);
          sw0+=wv; sp0+=wv*q.w; se0+=wv*ecc; }
        { float dx=P1.x-q.x, dy=P1.y-q.y, dz=P1.z-q.z;
          float wv = exp2f((dx*dx+dy*dy+dz*dz)*C);
          sw1+=wv; sp1+=wv*q.w; se1+=wv*ecc; }
    }
    float4* part = (float4*)(ws + WS_PART);
    part[c*NE + e0      ] = make_float4(sw0, sp0, se0, 0.f);
    part[c*NE + e0 + 256] = make_float4(sw1, sp1, se1, 0.f);
}

// Reduce chunk partials -> render params; also zero the map + init per-b max.
__global__ __launch_bounds__(256) void k_params(float* __restrict__ ws) {
    int e = blockIdx.x*256 + threadIdx.x;    // 32 blocks -> 8192
    // zero map: 131072 float4 over 8192 threads = 16 each, coalesced
    float4* mp = (float4*)(ws + WS_MAP);
    #pragma unroll
    for (int k = 0; k < 16; ++k) mp[k*8192 + e] = make_float4(0.f,0.f,0.f,0.f);
    if (e < NB) ws[WS_MAX + e] = 0.f;        // init for atomicMax
    const float4* part = (const float4*)(ws + WS_PART);
    float sw = 0.f, sp = 0.f, se = 0.f;
    #pragma unroll 8
    for (int c = 0; c < NCHUNK; ++c) {
        float4 p = part[c*NE + e];
        sw += p.x; sp += p.y; se += p.z;
    }
    if (e >= NB*NN) return;
    float denom = sw + 1e-8f;
    float pol = sp/denom, eccv = se/denom;
    float validity = fminf(sw, 1.f);
    float prob = ((const float4*)(ws + WS_EPOS))[e].w;
    float wgt = prob * validity;
    float ang = pol * 0.017453292519943295f;
    float m1 = 17.3f*(1.f/(eccv+0.75f) - 1.f/(eccv+120.f));
    float minv = 1.f/(fabsf(m1)+1e-8f);
    float sig  = 0.3849001794597506f * minv * 0.5f;   // sqrt(100/675)*m_inv/2
    const float scl = 256.f/90.f;
    float s = fmaxf(sig*scl, 1.f);                    // provably == 1.0 (ecc<=12)
    float invden = 1.f/(s*s + 1e-8f);
    ((float4*)(ws + WS_PAR4))[e] =
        make_float4(eccv*cosf(ang)*scl + 128.f, eccv*sinf(ang)*scl + 128.f, invden, wgt);
}

// One wave per electrode: 10x10 window ([-4,+5] around floor covers every pixel
// with d2 <= 20.25; beyond that exp <= 1.6e-9 -> negligible vs 2e-2 threshold).
__global__ __launch_bounds__(256) void k_render(float* __restrict__ ws) {
    int wid  = blockIdx.x*4 + (threadIdx.x >> 6);   // 2000 blocks x 4 waves = 8000
    int lane = threadIdx.x & 63;
    float4 p = ((const float4*)(ws + WS_PAR4))[wid];
    if (p.w <= 0.f) return;                 // wave-uniform
    int b  = wid / NN;
    int fx = (int)floorf(p.x), fy = (int)floorf(p.y);
    float* m = ws + WS_MAP + b*65536;
    #pragma unroll
    for (int pass = 0; pass < 2; ++pass) {
        int i = pass*64 + lane;
        if (i < 100) {
            int iy = i / 10, ix = i - iy*10;
            int X = fx - 4 + ix, Y = fy - 4 + iy;
            if (X >= 0 && X < 256 && Y >= 0 && Y < 256) {
                float dx = (float)X - p.x, dy = (float)Y - p.y;
                float d2 = dx*dx + dy*dy;
                if (d2 <= 20.25f)
                    atomicAdd(m + Y*256 + X, p.w * __expf(-d2 * p.z));
            }
        }
    }
}

// Per-b max via 16 blocks/b + uint atomicMax (valid for non-negative floats).
__global__ __launch_bounds__(256) void k_max(float* __restrict__ ws) {
    int g = blockIdx.x;                     // 128
    int b = g >> 4;
    const float4* m = (const float4*)(ws + WS_MAP + b*65536 + (g & 15)*4096);
    float mx = 0.f;
    #pragma unroll
    for (int k = 0; k < 4; ++k) {
        float4 v = m[k*256 + threadIdx.x];
        mx = fmaxf(mx, fmaxf(fmaxf(v.x, v.y), fmaxf(v.z, v.w)));
    }
    #pragma unroll
    for (int s2 = 32; s2 >= 1; s2 >>= 1) mx = fmaxf(mx, __shfl_xor(mx, s2, 64));
    __shared__ float red[4];
    if ((threadIdx.x & 63) == 0) red[threadIdx.x >> 6] = mx;
    __syncthreads();
    if (threadIdx.x == 0) {
        mx = fmaxf(fmaxf(red[0], red[1]), fmaxf(red[2], red[3]));
        atomicMax((unsigned int*)(ws + WS_MAX + b), __float_as_uint(mx));
    }
}

// rot90 + normalize via padded LDS tile: out[b,r,c] = raw[b, c, 255-r] / max.
__global__ __launch_bounds__(256) void k_final(const float* __restrict__ ws,
                                               float* __restrict__ out) {
    __shared__ float tile[32][33];
    int g  = blockIdx.x;                    // 512 = 8 b x 64 tiles
    int b  = g >> 6;
    int t6 = g & 63;
    int r0 = (t6 >> 3) * 32;
    int c0 = (t6 & 7) * 32;
    int ic0 = 224 - r0;                     // input col start = 255 - r0 - 31
    int j  = threadIdx.x & 31;
    int i0 = threadIdx.x >> 5;
    const float* m = ws + WS_MAP + b*65536;
    #pragma unroll
    for (int p = 0; p < 4; ++p) {
        int i = i0 + p*8;
        tile[i][j] = m[(c0+i)*256 + ic0 + j];   // coalesced load
    }
    __syncthreads();
    float inv = 1.f/(ws[WS_MAX + b] + 1e-8f);
    #pragma unroll
    for (int p = 0; p < 4; ++p) {
        int k = i0 + p*8;
        out[b*65536 + (r0+k)*256 + c0 + j] = tile[j][31-k] * inv;  // coalesced store
    }
}

extern "C" void kernel_launch(void* const* d_in, const int* in_sizes, int n_in,
                              void* d_out, int out_size, void* d_ws, size_t ws_size,
                              hipStream_t stream) {
    const float* params    = (const float*)d_in[0];
    const float* logits    = (const float*)d_in[1];
    const float* v1_pos    = (const float*)d_in[2];
    const float* v1_prf    = (const float*)d_in[3];
    const float* start_loc = (const float*)d_in[4];
    const float* lut       = (const float*)d_in[5];
    const float* agrid     = (const float*)d_in[6];
    const float* bgrid     = (const float*)d_in[7];
    const float* tmpl      = (const float*)d_in[8];
    float* ws  = (float*)d_ws;
    float* out = (float*)d_out;

    k_packepos<<<40,   256, 0, stream>>>(v1_pos, v1_prf, logits, tmpl,
                                         params, start_loc, lut, agrid, bgrid, ws);
    k_weights <<<2048, 256, 0, stream>>>(ws);
    k_params  <<<32,   256, 0, stream>>>(ws);
    k_render  <<<2000, 256, 0, stream>>>(ws);
    k_max     <<<128,  256, 0, stream>>>(ws);
    k_final   <<<512,  256, 0, stream>>>(ws, out);
}

// Round 5
// 131.375 us; speedup vs baseline: 1.1585x; 1.1585x over previous
//
#include <hip/hip_runtime.h>
#include <math.h>

// ---- workspace layout (float offsets); ws ~268 MB, we use ~19 MB ----
#define WS_MAP      0            // 524288: B x 256 x 256 raw map
#define WS_PART     524288       // 128 chunks x 8192 x float4 partials (16 MB)
#define WS_SETUP    4718592      // 104 floats: 8 x 13 (R[9], center[3], shank)
#define WS_MAX      4718720      // 8 per-b max

#define NB 8
#define NN 1000
#define NV 10000
#define NE 8192                  // padded electrode stride
#define NCHUNK 128
#define CHUNK 80                 // 128 x 80 = 10240 (padded V)

// Per-batch setup: rotation, direction, LUT bilinear interp, grid center.
__global__ void k_setup(const float* __restrict__ params,
                        const float* __restrict__ start_loc,
                        const float* __restrict__ lut,
                        const float* __restrict__ agrid,
                        const float* __restrict__ bgrid,
                        float* __restrict__ ws) {
    int b = threadIdx.x;
    if (b >= NB) return;
    float alpha = params[b*4+0], beta = params[b*4+1];
    float off   = params[b*4+2], shank = params[b*4+3];
    const float D2R = 0.017453292519943295f;
    float a = alpha*D2R, bb = beta*D2R;
    float ca = cosf(a), sa = sinf(a), cb = cosf(bb), sb = sinf(bb);
    // R = Rx(alpha) @ Ry(beta)
    float r00=cb,     r01=0.f, r02=sb;
    float r10=sa*sb,  r11=ca,  r12=-sa*cb;
    float r20=-ca*sb, r21=sa,  r22=ca*cb;
    // direction = normalize(R @ (0,0,-1)) = -col2
    float dx=-r02, dy=-r12, dz=-r22;
    float inv = rsqrtf(dx*dx+dy*dy+dz*dz);
    dx*=inv; dy*=inv; dz*=inv;
    // bilinear interp of 37x26 LUT, matching reference arithmetic
    float ag0=agrid[0], agN=agrid[36], bg0=bgrid[0], bgN=bgrid[25];
    float an = 2.f*(alpha-ag0)/(agN-ag0+1e-8f) - 1.f;
    float bn = 2.f*(beta -bg0)/(bgN-bg0+1e-8f) - 1.f;
    float ai = fminf(fmaxf((an+1.f)*0.5f*36.f, 0.f), 36.f);
    float bi = fminf(fmaxf((bn+1.f)*0.5f*25.f, 0.f), 25.f);
    int a0 = (int)floorf(ai); a0 = a0<0?0:(a0>36?36:a0);
    int b0 = (int)floorf(bi); b0 = b0<0?0:(b0>25?25:b0);
    int a1 = a0+1>36?36:a0+1;
    int b1 = b0+1>25?25:b0+1;
    float fa = ai - (float)a0, fb = bi - (float)b0;
    float v00=lut[a0*26+b0], v01=lut[a0*26+b1], v10=lut[a1*26+b0], v11=lut[a1*26+b1];
    float sd = v00*(1.f-fa)*(1.f-fb) + v01*(1.f-fa)*fb + v10*fa*(1.f-fb) + v11*fa*fb;
    sd = fmaxf(sd, 1.f);
    float pen = sd - shank*0.5f - off;
    float* o = ws + WS_SETUP + b*13;
    o[0]=r00; o[1]=r01; o[2]=r02; o[3]=r10; o[4]=r11; o[5]=r12;
    o[6]=r20; o[7]=r21; o[8]=r22;
    o[9]  = start_loc[0] + dx*pen;
    o[10] = start_loc[1] + dy*pen;
    o[11] = start_loc[2] + dz*pen;
    o[12] = shank;
}

// Soft-match, 4 electrodes/thread, expanded-d2 form (matches reference numerics:
// p2 + v2 - 2*cross). LDS point pre-scaled: sq = (-2C x, -2C y, -2C z, C|q|^2);
// arg = C|P|^2 + sq.w + sq.xyz . P; wv = exp2(arg). 8 VALU + 1 v_exp per pair.
// 1024 blocks = 128 V-chunks x 8 electrode groups; 4 blocks/CU (16 waves/CU).
// Also zeroes the map (1024 x 512 floats) and inits per-b max.
__global__ __launch_bounds__(256, 4) void k_weights(const float* __restrict__ v1_pos,
                                                    const float* __restrict__ v1_prf,
                                                    const float* __restrict__ tmpl,
                                                    float* __restrict__ ws) {
    __shared__ float4 sq[CHUNK];
    __shared__ float2 spe[CHUNK];
    __shared__ float  sst[NB*13];
    int g = blockIdx.x, t = threadIdx.x;
    int c = g >> 3, eg = g & 7;
    // zero map slice: 1024 blocks x 256 float2 = full 2 MB map
    ((float2*)(ws + WS_MAP))[g*256 + t] = make_float2(0.f, 0.f);
    if (g == 0 && t < NB) ws[WS_MAX + t] = 0.f;
    if (t < NB*13) sst[t] = ws[WS_SETUP + t];
    const float C = -0.32059889797532524f;   // -log2(e)/4.5
    if (t < CHUNK) {
        int v = c*CHUNK + t;
        if (v < NV) {
            float x = v1_pos[v*3], y = v1_pos[v*3+1], z = v1_pos[v*3+2];
            sq[t]  = make_float4(-2.f*C*x, -2.f*C*y, -2.f*C*z, C*(x*x+y*y+z*z));
            spe[t] = make_float2(v1_prf[v*3], v1_prf[v*3+1]);
        } else {                              // padded V -> wv == 0 exactly
            sq[t]  = make_float4(0.f, 0.f, 0.f, -1e30f);
            spe[t] = make_float2(0.f, 0.f);
        }
    }
    __syncthreads();
    int e0 = eg*1024 + t;                     // electrodes e0 + {0,256,512,768}
    float Px[4], Py[4], Pz[4], A[4];
    #pragma unroll
    for (int j = 0; j < 4; ++j) {
        int e = e0 + j*256;
        if (e < NB*NN) {
            int b = e/1000, n = e - b*1000;
            const float* st = sst + b*13;
            // centered grid point (template means are analytically 1.8, 1.8, 0.5)
            float gx = tmpl[n*3]-1.8f, gy = tmpl[n*3+1]-1.8f;
            float gz = (tmpl[n*3+2]-0.5f)*st[12];
            float px = st[0]*gx + st[1]*gy + st[2]*gz + st[9];
            float py = st[3]*gx + st[4]*gy + st[5]*gz + st[10];
            float pz = st[6]*gx + st[7]*gy + st[8]*gz + st[11];
            Px[j]=px; Py[j]=py; Pz[j]=pz; A[j]=C*(px*px+py*py+pz*pz);
        } else { Px[j]=0.f; Py[j]=0.f; Pz[j]=0.f; A[j]=-1e30f; }  // partial unread
    }
    float sw[4]={0,0,0,0}, sp[4]={0,0,0,0}, se[4]={0,0,0,0};
    #pragma unroll 2
    for (int i = 0; i < CHUNK; ++i) {
        float4 q = sq[i];
        float2 pe = spe[i];
        #pragma unroll
        for (int j = 0; j < 4; ++j) {
            float arg = fmaf(q.x, Px[j], fmaf(q.y, Py[j], fmaf(q.z, Pz[j], A[j] + q.w)));
            float wv = __builtin_amdgcn_exp2f(arg);   // v_exp_f32, no libcall
            sw[j] += wv;
            sp[j] = fmaf(wv, pe.x, sp[j]);
            se[j] = fmaf(wv, pe.y, se[j]);
        }
    }
    float4* part = (float4*)(ws + WS_PART);
    #pragma unroll
    for (int j = 0; j < 4; ++j)
        part[c*NE + e0 + j*256] = make_float4(sw[j], sp[j], se[j], 0.f);
}

// Fused params+render: one wave per electrode (2000 blocks x 4 waves = 8000).
// Wave reduces its 128 chunk-partials (2 loads + butterfly), all lanes compute
// params redundantly, then render the 10x10 window ([-4,+5] covers all pixels
// with d2 <= 20.25; beyond that exp <= 1.6e-9, negligible vs 2e-2 threshold).
__global__ __launch_bounds__(256) void k_prender(const float* __restrict__ logits,
                                                 float* __restrict__ ws) {
    int e    = blockIdx.x*4 + (threadIdx.x >> 6);
    int lane = threadIdx.x & 63;
    const float4* part = (const float4*)(ws + WS_PART);
    float4 p0 = part[lane*NE + e];
    float4 p1 = part[(lane+64)*NE + e];
    float sw = p0.x + p1.x, sp = p0.y + p1.y, se = p0.z + p1.z;
    #pragma unroll
    for (int m = 1; m < 64; m <<= 1) {
        sw += __shfl_xor(sw, m, 64);
        sp += __shfl_xor(sp, m, 64);
        se += __shfl_xor(se, m, 64);
    }
    float denom = sw + 1e-8f;
    float pol = sp/denom, eccv = se/denom;
    float validity = fminf(sw, 1.f);
    float prob = 1.f/(1.f + __expf(-logits[e]));
    float wgt = prob * validity;
    if (wgt <= 0.f) return;                  // wave-uniform
    float ang = pol * 0.017453292519943295f;
    float m1 = 17.3f*(1.f/(eccv+0.75f) - 1.f/(eccv+120.f));
    float minv = 1.f/(fabsf(m1)+1e-8f);
    float sig  = 0.3849001794597506f * minv * 0.5f;   // sqrt(100/675)*m_inv/2
    const float scl = 256.f/90.f;
    float s = fmaxf(sig*scl, 1.f);                    // provably == 1.0 (ecc<=12)
    float invden = 1.f/(s*s + 1e-8f);
    float cx = eccv*__cosf(ang)*scl + 128.f;
    float cy = eccv*__sinf(ang)*scl + 128.f;
    int b = e/1000;
    int fx = (int)floorf(cx), fy = (int)floorf(cy);
    float* mp = ws + WS_MAP + b*65536;
    #pragma unroll
    for (int pass = 0; pass < 2; ++pass) {
        int i = pass*64 + lane;
        if (i < 100) {
            int iy = i/10, ix = i - iy*10;
            int X = fx - 4 + ix, Y = fy - 4 + iy;
            if (X >= 0 && X < 256 && Y >= 0 && Y < 256) {
                float dx = (float)X - cx, dy = (float)Y - cy;
                float d2 = dx*dx + dy*dy;
                if (d2 <= 20.25f)
                    atomicAdd(mp + Y*256 + X, wgt * __expf(-d2 * invden));
            }
        }
    }
}

// Per-b max via 16 blocks/b + uint atomicMax (valid for non-negative floats).
__global__ __launch_bounds__(256) void k_max(float* __restrict__ ws) {
    int g = blockIdx.x;                     // 128
    int b = g >> 4;
    const float4* m = (const float4*)(ws + WS_MAP + b*65536 + (g & 15)*4096);
    float mx = 0.f;
    #pragma unroll
    for (int k = 0; k < 4; ++k) {
        float4 v = m[k*256 + threadIdx.x];
        mx = fmaxf(mx, fmaxf(fmaxf(v.x, v.y), fmaxf(v.z, v.w)));
    }
    #pragma unroll
    for (int s2 = 32; s2 >= 1; s2 >>= 1) mx = fmaxf(mx, __shfl_xor(mx, s2, 64));
    __shared__ float red[4];
    if ((threadIdx.x & 63) == 0) red[threadIdx.x >> 6] = mx;
    __syncthreads();
    if (threadIdx.x == 0) {
        mx = fmaxf(fmaxf(red[0], red[1]), fmaxf(red[2], red[3]));
        atomicMax((unsigned int*)(ws + WS_MAX + b), __float_as_uint(mx));
    }
}

// rot90 + normalize via padded LDS tile: out[b,r,c] = raw[b, c, 255-r] / max.
__global__ __launch_bounds__(256) void k_final(const float* __restrict__ ws,
                                               float* __restrict__ out) {
    __shared__ float tile[32][33];
    int g  = blockIdx.x;                    // 512 = 8 b x 64 tiles
    int b  = g >> 6;
    int t6 = g & 63;
    int r0 = (t6 >> 3) * 32;
    int c0 = (t6 & 7) * 32;
    int ic0 = 224 - r0;                     // input col start = 255 - r0 - 31
    int j  = threadIdx.x & 31;
    int i0 = threadIdx.x >> 5;
    const float* m = ws + WS_MAP + b*65536;
    #pragma unroll
    for (int p = 0; p < 4; ++p) {
        int i = i0 + p*8;
        tile[i][j] = m[(c0+i)*256 + ic0 + j];   // coalesced load
    }
    __syncthreads();
    float inv = 1.f/(ws[WS_MAX + b] + 1e-8f);
    #pragma unroll
    for (int p = 0; p < 4; ++p) {
        int k = i0 + p*8;
        out[b*65536 + (r0+k)*256 + c0 + j] = tile[j][31-k] * inv;  // coalesced store
    }
}

extern "C" void kernel_launch(void* const* d_in, const int* in_sizes, int n_in,
                              void* d_out, int out_size, void* d_ws, size_t ws_size,
                              hipStream_t stream) {
    const float* params    = (const float*)d_in[0];
    const float* logits    = (const float*)d_in[1];
    const float* v1_pos    = (const float*)d_in[2];
    const float* v1_prf    = (const float*)d_in[3];
    const float* start_loc = (const float*)d_in[4];
    const float* lut       = (const float*)d_in[5];
    const float* agrid     = (const float*)d_in[6];
    const float* bgrid     = (const float*)d_in[7];
    const float* tmpl      = (const float*)d_in[8];
    float* ws  = (float*)d_ws;
    float* out = (float*)d_out;

    k_setup  <<<1,    64,  0, stream>>>(params, start_loc, lut, agrid, bgrid, ws);
    k_weights<<<1024, 256, 0, stream>>>(v1_pos, v1_prf, tmpl, ws);
    k_prender<<<2000, 256, 0, stream>>>(logits, ws);
    k_max    <<<128,  256, 0, stream>>>(ws);
    k_final  <<<512,  256, 0, stream>>>(ws, out);
}

// Round 6
// 130.743 us; speedup vs baseline: 1.1641x; 1.0048x over previous
//
#include <hip/hip_runtime.h>
#include <math.h>

// ---- workspace layout (float offsets); ws ~268 MB, we use ~36 MB ----
#define WS_MAP      0            // 524288: B x 256 x 256 raw map
#define WS_PART     524288       // 256 chunks x 8192 x float4 partials (33.5 MB)

#define NB 8
#define NN 1000
#define NV 10000
#define NE 8192                  // padded electrode stride
#define NCHUNK 256
#define CHUNK 40                 // 256 x 40 = 10240 (padded V)

// Soft-match, 8 electrodes/thread, expanded-d2 form (matches reference numerics:
// p2 + v2 - 2*cross). LDS point pre-scaled: sq = (-2C x, -2C y, -2C z, C|q|^2);
// arg = C|P|^2 + sq.w + sq.xyz . P; wv = exp2(arg). ~8 VALU + 1 v_exp per pair,
// 3 B LDS per pair. 1024 blocks = 256 V-chunks x 4 electrode groups.
// Per-batch setup (rotation/LUT/center) computed redundantly per block (trivial,
// pre-barrier). Also zeroes the 2 MB map (1024 x 512 floats).
__global__ __launch_bounds__(256) void k_weights(const float* __restrict__ params,
                                                 const float* __restrict__ start_loc,
                                                 const float* __restrict__ lut,
                                                 const float* __restrict__ agrid,
                                                 const float* __restrict__ bgrid,
                                                 const float* __restrict__ v1_pos,
                                                 const float* __restrict__ v1_prf,
                                                 const float* __restrict__ tmpl,
                                                 float* __restrict__ ws) {
    __shared__ float4 sq[CHUNK];
    __shared__ float2 spe[CHUNK];
    __shared__ float  sst[NB*13];
    int g = blockIdx.x, t = threadIdx.x;
    int c = g >> 2, eg = g & 3;
    // zero map slice: 1024 blocks x 256 float2 = full 2 MB map
    ((float2*)(ws + WS_MAP))[g*256 + t] = make_float2(0.f, 0.f);
    const float C = -0.32059889797532524f;   // -log2(e)/4.5
    if (t < NB) {    // inline per-batch setup
        int b = t;
        float alpha = params[b*4+0], beta = params[b*4+1];
        float off   = params[b*4+2], shank = params[b*4+3];
        const float D2R = 0.017453292519943295f;
        float a = alpha*D2R, bb = beta*D2R;
        float ca = cosf(a), sa = sinf(a), cb = cosf(bb), sb = sinf(bb);
        // R = Rx(alpha) @ Ry(beta)
        float r00=cb,     r01=0.f, r02=sb;
        float r10=sa*sb,  r11=ca,  r12=-sa*cb;
        float r20=-ca*sb, r21=sa,  r22=ca*cb;
        // direction = normalize(R @ (0,0,-1)) = -col2
        float dx=-r02, dy=-r12, dz=-r22;
        float inv = rsqrtf(dx*dx+dy*dy+dz*dz);
        dx*=inv; dy*=inv; dz*=inv;
        // bilinear interp of 37x26 LUT, matching reference arithmetic
        float ag0=agrid[0], agN=agrid[36], bg0=bgrid[0], bgN=bgrid[25];
        float an = 2.f*(alpha-ag0)/(agN-ag0+1e-8f) - 1.f;
        float bn = 2.f*(beta -bg0)/(bgN-bg0+1e-8f) - 1.f;
        float ai = fminf(fmaxf((an+1.f)*0.5f*36.f, 0.f), 36.f);
        float bi = fminf(fmaxf((bn+1.f)*0.5f*25.f, 0.f), 25.f);
        int a0 = (int)floorf(ai); a0 = a0<0?0:(a0>36?36:a0);
        int b0 = (int)floorf(bi); b0 = b0<0?0:(b0>25?25:b0);
        int a1 = a0+1>36?36:a0+1;
        int b1 = b0+1>25?25:b0+1;
        float fa = ai - (float)a0, fb = bi - (float)b0;
        float v00=lut[a0*26+b0], v01=lut[a0*26+b1], v10=lut[a1*26+b0], v11=lut[a1*26+b1];
        float sd = v00*(1.f-fa)*(1.f-fb) + v01*(1.f-fa)*fb + v10*fa*(1.f-fb) + v11*fa*fb;
        sd = fmaxf(sd, 1.f);
        float pen = sd - shank*0.5f - off;
        sst[b*13+0]=r00; sst[b*13+1]=r01; sst[b*13+2]=r02;
        sst[b*13+3]=r10; sst[b*13+4]=r11; sst[b*13+5]=r12;
        sst[b*13+6]=r20; sst[b*13+7]=r21; sst[b*13+8]=r22;
        sst[b*13+9]  = start_loc[0] + dx*pen;
        sst[b*13+10] = start_loc[1] + dy*pen;
        sst[b*13+11] = start_loc[2] + dz*pen;
        sst[b*13+12] = shank;
    }
    if (t < CHUNK) {   // stage this block's v1 chunk
        int v = c*CHUNK + t;
        if (v < NV) {
            float x = v1_pos[v*3], y = v1_pos[v*3+1], z = v1_pos[v*3+2];
            sq[t]  = make_float4(-2.f*C*x, -2.f*C*y, -2.f*C*z, C*(x*x+y*y+z*z));
            spe[t] = make_float2(v1_prf[v*3], v1_prf[v*3+1]);
        } else {                              // padded V -> wv == 0 exactly
            sq[t]  = make_float4(0.f, 0.f, 0.f, -1e30f);
            spe[t] = make_float2(0.f, 0.f);
        }
    }
    __syncthreads();
    int e0 = eg*2048 + t;                     // electrodes e0 + j*256, j<8
    float Px[8], Py[8], Pz[8], A[8];
    #pragma unroll
    for (int j = 0; j < 8; ++j) {
        int e = e0 + j*256;
        if (e < NB*NN) {
            int b = e/1000, n = e - b*1000;
            const float* st = sst + b*13;
            // centered grid point (template means are analytically 1.8, 1.8, 0.5)
            float gx = tmpl[n*3]-1.8f, gy = tmpl[n*3+1]-1.8f;
            float gz = (tmpl[n*3+2]-0.5f)*st[12];
            float px = st[0]*gx + st[1]*gy + st[2]*gz + st[9];
            float py = st[3]*gx + st[4]*gy + st[5]*gz + st[10];
            float pz = st[6]*gx + st[7]*gy + st[8]*gz + st[11];
            Px[j]=px; Py[j]=py; Pz[j]=pz; A[j]=C*(px*px+py*py+pz*pz);
        } else { Px[j]=0.f; Py[j]=0.f; Pz[j]=0.f; A[j]=-1e30f; }  // partial unread
    }
    float sw[8], sp[8], se[8];
    #pragma unroll
    for (int j = 0; j < 8; ++j) { sw[j]=0.f; sp[j]=0.f; se[j]=0.f; }
    #pragma unroll 2
    for (int i = 0; i < CHUNK; ++i) {
        float4 q = sq[i];
        float2 pe = spe[i];
        #pragma unroll
        for (int j = 0; j < 8; ++j) {
            float arg = fmaf(q.x, Px[j], fmaf(q.y, Py[j], fmaf(q.z, Pz[j], A[j] + q.w)));
            float wv = __builtin_amdgcn_exp2f(arg);   // v_exp_f32, no libcall
            sw[j] += wv;
            sp[j] = fmaf(wv, pe.x, sp[j]);
            se[j] = fmaf(wv, pe.y, se[j]);
        }
    }
    float4* part = (float4*)(ws + WS_PART);
    #pragma unroll
    for (int j = 0; j < 8; ++j)
        part[c*NE + e0 + j*256] = make_float4(sw[j], sp[j], se[j], 0.f);
}

// Fused params+render: one wave per electrode (2000 blocks x 4 waves = 8000).
// Wave reduces its 256 chunk-partials (4 loads + butterfly), all lanes compute
// params redundantly, then render an 8x8 window ([-3,+4] covers all pixels with
// d2 <= 12.25; beyond that exp <= 4.8e-6 -> truncation <= ~5e-3 pre-norm, well
// under the 2e-2 threshold).
__global__ __launch_bounds__(256) void k_prender(const float* __restrict__ logits,
                                                 float* __restrict__ ws) {
    int e    = blockIdx.x*4 + (threadIdx.x >> 6);
    int lane = threadIdx.x & 63;
    const float4* part = (const float4*)(ws + WS_PART);
    float4 p0 = part[ lane       *NE + e];
    float4 p1 = part[(lane +  64)*NE + e];
    float4 p2 = part[(lane + 128)*NE + e];
    float4 p3 = part[(lane + 192)*NE + e];
    float sw = (p0.x+p1.x) + (p2.x+p3.x);
    float sp = (p0.y+p1.y) + (p2.y+p3.y);
    float se = (p0.z+p1.z) + (p2.z+p3.z);
    #pragma unroll
    for (int m = 1; m < 64; m <<= 1) {
        sw += __shfl_xor(sw, m, 64);
        sp += __shfl_xor(sp, m, 64);
        se += __shfl_xor(se, m, 64);
    }
    float denom = sw + 1e-8f;
    float pol = sp/denom, eccv = se/denom;
    float validity = fminf(sw, 1.f);
    float prob = 1.f/(1.f + __expf(-logits[e]));
    float wgt = prob * validity;
    if (wgt <= 0.f) return;                  // wave-uniform
    float ang = pol * 0.017453292519943295f;
    float m1 = 17.3f*(1.f/(eccv+0.75f) - 1.f/(eccv+120.f));
    float minv = 1.f/(fabsf(m1)+1e-8f);
    float sig  = 0.3849001794597506f * minv * 0.5f;   // sqrt(100/675)*m_inv/2
    const float scl = 256.f/90.f;
    float s = fmaxf(sig*scl, 1.f);                    // provably == 1.0 (ecc<=12)
    float invden = 1.f/(s*s + 1e-8f);
    float cx = eccv*__cosf(ang)*scl + 128.f;
    float cy = eccv*__sinf(ang)*scl + 128.f;
    int b = e/1000;
    int fx = (int)floorf(cx), fy = (int)floorf(cy);
    float* mp = ws + WS_MAP + b*65536;
    int ix = lane & 7, iy = lane >> 3;       // 8x8, one pass of 64 lanes
    int X = fx - 3 + ix, Y = fy - 3 + iy;
    if (X >= 0 && X < 256 && Y >= 0 && Y < 256) {
        float dx = (float)X - cx, dy = (float)Y - cy;
        float d2 = dx*dx + dy*dy;
        if (d2 <= 12.25f)
            atomicAdd(mp + Y*256 + X, wgt * __expf(-d2 * invden));
    }
}

// Fused max + rot90 + normalize: one block per b (1024 threads).
// Phase 1: block max. Phase 2: per-wave 16x16 LDS tiles (wave-private buffers,
// in-wave ds ordering -> no block barriers): out[b,r,c] = raw[b, c, 255-r]/max.
__global__ __launch_bounds__(1024) void k_maxfinal(const float* __restrict__ ws,
                                                   float* __restrict__ out) {
    int b = blockIdx.x, tid = threadIdx.x;
    const float4* m4 = (const float4*)(ws + WS_MAP + b*65536);
    float mx = 0.f;   // map values >= 0
    #pragma unroll
    for (int k = 0; k < 16; ++k) {
        float4 v = m4[k*1024 + tid];
        mx = fmaxf(mx, fmaxf(fmaxf(v.x, v.y), fmaxf(v.z, v.w)));
    }
    #pragma unroll
    for (int s2 = 32; s2 >= 1; s2 >>= 1) mx = fmaxf(mx, __shfl_xor(mx, s2, 64));
    __shared__ float red[16];
    int w = tid >> 6, lane = tid & 63;
    if (lane == 0) red[w] = mx;
    __syncthreads();
    float gm = red[0];
    #pragma unroll
    for (int k = 1; k < 16; ++k) gm = fmaxf(gm, red[k]);
    float inv = 1.f/(gm + 1e-8f);
    __shared__ float tile[16][16][17];       // per-wave buffers
    const float* m = ws + WS_MAP + b*65536;
    float* ob = out + b*65536;
    int jj = lane & 15, qq = lane >> 4;      // 0..15, 0..3
    for (int tt = 0; tt < 16; ++tt) {
        int t6 = w*16 + tt;                  // tile 0..255
        int r0 = (t6 >> 4) * 16;
        int c0 = (t6 & 15) * 16;
        int ic0 = 240 - r0;                  // input col start = 255 - r0 - 15
        #pragma unroll
        for (int k = 0; k < 4; ++k) {
            int i = qq + k*4;
            tile[w][i][jj] = m[(c0+i)*256 + ic0 + jj];
        }
        // same-wave LDS write->read: ordered via lgkmcnt, no barrier needed
        #pragma unroll
        for (int k = 0; k < 4; ++k) {
            int kk = qq + k*4;
            ob[(r0+kk)*256 + c0 + jj] = tile[w][jj][15-kk] * inv;
        }
    }
}

extern "C" void kernel_launch(void* const* d_in, const int* in_sizes, int n_in,
                              void* d_out, int out_size, void* d_ws, size_t ws_size,
                              hipStream_t stream) {
    const float* params    = (const float*)d_in[0];
    const float* logits    = (const float*)d_in[1];
    const float* v1_pos    = (const float*)d_in[2];
    const float* v1_prf    = (const float*)d_in[3];
    const float* start_loc = (const float*)d_in[4];
    const float* lut       = (const float*)d_in[5];
    const float* agrid     = (const float*)d_in[6];
    const float* bgrid     = (const float*)d_in[7];
    const float* tmpl      = (const float*)d_in[8];
    float* ws  = (float*)d_ws;
    float* out = (float*)d_out;

    k_weights <<<1024, 256,  0, stream>>>(params, start_loc, lut, agrid, bgrid,
                                          v1_pos, v1_prf, tmpl, ws);
    k_prender <<<2000, 256,  0, stream>>>(logits, ws);
    k_maxfinal<<<8,    1024, 0, stream>>>(ws, out);
}

// Round 7
// 125.473 us; speedup vs baseline: 1.2130x; 1.0420x over previous
//
#include <hip/hip_runtime.h>
#include <math.h>

// ---- workspace layout (float offsets); ws ~268 MB, we use ~36 MB ----
#define WS_MAP      0            // 524288: B x 256 x 256 raw map
#define WS_PART     524288       // 256 chunks x 8192 x float4 partials (33.5 MB)
#define WS_MAX      8912896      // 8 per-b max (after partials)

#define NB 8
#define NN 1000
#define NV 10000
#define NE 8192                  // padded electrode stride
#define NCHUNK 256
#define CHUNK 40                 // 256 x 40 = 10240 (padded V)

// Soft-match, 8 electrodes/thread, expanded-d2 form (matches reference numerics:
// p2 + v2 - 2*cross). LDS point pre-scaled: sq = (-2C x, -2C y, -2C z, C|q|^2);
// arg = C|P|^2 + sq.w + sq.xyz . P; wv = exp2(arg). ~7 VALU + 1 v_exp per pair.
// 1024 blocks = 256 V-chunks x 4 electrode groups (4 blocks/CU).
// Per-batch setup computed redundantly per block (trivial, pre-barrier).
// Also zeroes the 2 MB map and inits the per-b max slots.
__global__ __launch_bounds__(256) void k_weights(const float* __restrict__ params,
                                                 const float* __restrict__ start_loc,
                                                 const float* __restrict__ lut,
                                                 const float* __restrict__ agrid,
                                                 const float* __restrict__ bgrid,
                                                 const float* __restrict__ v1_pos,
                                                 const float* __restrict__ v1_prf,
                                                 const float* __restrict__ tmpl,
                                                 float* __restrict__ ws) {
    __shared__ float4 sq[CHUNK];
    __shared__ float2 spe[CHUNK];
    __shared__ float  sst[NB*13];
    int g = blockIdx.x, t = threadIdx.x;
    int c = g >> 2, eg = g & 3;
    // zero map slice: 1024 blocks x 256 float2 = full 2 MB map
    ((float2*)(ws + WS_MAP))[g*256 + t] = make_float2(0.f, 0.f);
    if (g == 0 && t < NB) ws[WS_MAX + t] = 0.f;   // init for k_max atomicMax
    const float C = -0.32059889797532524f;   // -log2(e)/4.5
    if (t < NB) {    // inline per-batch setup
        int b = t;
        float alpha = params[b*4+0], beta = params[b*4+1];
        float off   = params[b*4+2], shank = params[b*4+3];
        const float D2R = 0.017453292519943295f;
        float a = alpha*D2R, bb = beta*D2R;
        float ca = cosf(a), sa = sinf(a), cb = cosf(bb), sb = sinf(bb);
        // R = Rx(alpha) @ Ry(beta)
        float r00=cb,     r01=0.f, r02=sb;
        float r10=sa*sb,  r11=ca,  r12=-sa*cb;
        float r20=-ca*sb, r21=sa,  r22=ca*cb;
        // direction = normalize(R @ (0,0,-1)) = -col2
        float dx=-r02, dy=-r12, dz=-r22;
        float inv = rsqrtf(dx*dx+dy*dy+dz*dz);
        dx*=inv; dy*=inv; dz*=inv;
        // bilinear interp of 37x26 LUT, matching reference arithmetic
        float ag0=agrid[0], agN=agrid[36], bg0=bgrid[0], bgN=bgrid[25];
        float an = 2.f*(alpha-ag0)/(agN-ag0+1e-8f) - 1.f;
        float bn = 2.f*(beta -bg0)/(bgN-bg0+1e-8f) - 1.f;
        float ai = fminf(fmaxf((an+1.f)*0.5f*36.f, 0.f), 36.f);
        float bi = fminf(fmaxf((bn+1.f)*0.5f*25.f, 0.f), 25.f);
        int a0 = (int)floorf(ai); a0 = a0<0?0:(a0>36?36:a0);
        int b0 = (int)floorf(bi); b0 = b0<0?0:(b0>25?25:b0);
        int a1 = a0+1>36?36:a0+1;
        int b1 = b0+1>25?25:b0+1;
        float fa = ai - (float)a0, fb = bi - (float)b0;
        float v00=lut[a0*26+b0], v01=lut[a0*26+b1], v10=lut[a1*26+b0], v11=lut[a1*26+b1];
        float sd = v00*(1.f-fa)*(1.f-fb) + v01*(1.f-fa)*fb + v10*fa*(1.f-fb) + v11*fa*fb;
        sd = fmaxf(sd, 1.f);
        float pen = sd - shank*0.5f - off;
        sst[b*13+0]=r00; sst[b*13+1]=r01; sst[b*13+2]=r02;
        sst[b*13+3]=r10; sst[b*13+4]=r11; sst[b*13+5]=r12;
        sst[b*13+6]=r20; sst[b*13+7]=r21; sst[b*13+8]=r22;
        sst[b*13+9]  = start_loc[0] + dx*pen;
        sst[b*13+10] = start_loc[1] + dy*pen;
        sst[b*13+11] = start_loc[2] + dz*pen;
        sst[b*13+12] = shank;
    }
    if (t < CHUNK) {   // stage this block's v1 chunk
        int v = c*CHUNK + t;
        if (v < NV) {
            float x = v1_pos[v*3], y = v1_pos[v*3+1], z = v1_pos[v*3+2];
            sq[t]  = make_float4(-2.f*C*x, -2.f*C*y, -2.f*C*z, C*(x*x+y*y+z*z));
            spe[t] = make_float2(v1_prf[v*3], v1_prf[v*3+1]);
        } else {                              // padded V -> wv == 0 exactly
            sq[t]  = make_float4(0.f, 0.f, 0.f, -1e30f);
            spe[t] = make_float2(0.f, 0.f);
        }
    }
    __syncthreads();
    int e0 = eg*2048 + t;                     // electrodes e0 + j*256, j<8
    float Px[8], Py[8], Pz[8], A[8];
    #pragma unroll
    for (int j = 0; j < 8; ++j) {
        int e = e0 + j*256;
        if (e < NB*NN) {
            int b = e/1000, n = e - b*1000;
            const float* st = sst + b*13;
            // centered grid point (template means are analytically 1.8, 1.8, 0.5)
            float gx = tmpl[n*3]-1.8f, gy = tmpl[n*3+1]-1.8f;
            float gz = (tmpl[n*3+2]-0.5f)*st[12];
            float px = st[0]*gx + st[1]*gy + st[2]*gz + st[9];
            float py = st[3]*gx + st[4]*gy + st[5]*gz + st[10];
            float pz = st[6]*gx + st[7]*gy + st[8]*gz + st[11];
            Px[j]=px; Py[j]=py; Pz[j]=pz; A[j]=C*(px*px+py*py+pz*pz);
        } else { Px[j]=0.f; Py[j]=0.f; Pz[j]=0.f; A[j]=-1e30f; }  // -> sw == 0
    }
    float sw[8], sp[8], se[8];
    #pragma unroll
    for (int j = 0; j < 8; ++j) { sw[j]=0.f; sp[j]=0.f; se[j]=0.f; }
    #pragma unroll 2
    for (int i = 0; i < CHUNK; ++i) {
        float4 q = sq[i];
        float2 pe = spe[i];
        #pragma unroll
        for (int j = 0; j < 8; ++j) {
            float arg = fmaf(q.x, Px[j], fmaf(q.y, Py[j], fmaf(q.z, Pz[j], A[j] + q.w)));
            float wv = __builtin_amdgcn_exp2f(arg);   // v_exp_f32, no libcall
            sw[j] += wv;
            sp[j] = fmaf(wv, pe.x, sp[j]);
            se[j] = fmaf(wv, pe.y, se[j]);
        }
    }
    float4* part = (float4*)(ws + WS_PART);
    #pragma unroll
    for (int j = 0; j < 8; ++j)
        part[c*NE + e0 + j*256] = make_float4(sw[j], sp[j], se[j], 0.f);   // coalesced
}

// Fused params+render, 128 blocks x 64 electrodes.
// Phase A: wave w sums chunks c in [64w, 64w+64); lane = electrode -> every
//   load is a contiguous 1 KB segment (fully coalesced, no line amplification).
// Phase B: wave 0 reduces 4 wave-partials from LDS, computes render params.
// Phase C: each wave renders 16 electrodes' 8x8 windows ([-3,+4] covers all
//   pixels with d2 <= 12.25; beyond that exp <= 4.8e-6 -> truncation ~5e-3
//   pre-norm worst case, well under the 2e-2 threshold).
__global__ __launch_bounds__(256) void k_prender(const float* __restrict__ logits,
                                                 float* __restrict__ ws) {
    __shared__ float4 red[4][64];
    __shared__ float4 par[64];
    int E0 = blockIdx.x * 64;
    int t = threadIdx.x, lane = t & 63, w = t >> 6;
    const float4* part = (const float4*)(ws + WS_PART);
    float sw = 0.f, sp = 0.f, se = 0.f;
    int e = E0 + lane;
    #pragma unroll 8
    for (int i = 0; i < 64; ++i) {
        float4 p = part[(w*64 + i)*NE + e];
        sw += p.x; sp += p.y; se += p.z;
    }
    red[w][lane] = make_float4(sw, sp, se, 0.f);
    __syncthreads();
    if (w == 0) {
        float4 a = red[0][lane], b4 = red[1][lane], c4 = red[2][lane], d4 = red[3][lane];
        sw = (a.x+b4.x) + (c4.x+d4.x);
        sp = (a.y+b4.y) + (c4.y+d4.y);
        se = (a.z+b4.z) + (c4.z+d4.z);
        float denom = sw + 1e-8f;
        float pol = sp/denom, eccv = se/denom;
        float validity = fminf(sw, 1.f);
        float lg = (e < NB*NN) ? logits[e] : 0.f;     // guard padded electrodes
        float prob = 1.f/(1.f + __expf(-lg));
        float wgt = prob * validity;
        float ang = pol * 0.017453292519943295f;
        float m1 = 17.3f*(1.f/(eccv+0.75f) - 1.f/(eccv+120.f));
        float minv = 1.f/(fabsf(m1)+1e-8f);
        float sig  = 0.3849001794597506f * minv * 0.5f;   // sqrt(100/675)*m_inv/2
        const float scl = 256.f/90.f;
        float s = fmaxf(sig*scl, 1.f);                    // provably == 1.0 (ecc<=12)
        float invden = 1.f/(s*s + 1e-8f);
        par[lane] = make_float4(eccv*__cosf(ang)*scl + 128.f,
                                eccv*__sinf(ang)*scl + 128.f, invden, wgt);
    }
    __syncthreads();
    int ix = lane & 7, iy = lane >> 3;       // 8x8 window, one pass of 64 lanes
    for (int k = 0; k < 16; ++k) {
        int el = k*4 + w;
        float4 P = par[el];
        if (P.w <= 0.f) continue;            // wave-uniform (incl. padded e>=8000)
        int b = (E0 + el) / 1000;
        int fx = (int)floorf(P.x), fy = (int)floorf(P.y);
        int X = fx - 3 + ix, Y = fy - 3 + iy;
        if (X >= 0 && X < 256 && Y >= 0 && Y < 256) {
            float dx = (float)X - P.x, dy = (float)Y - P.y;
            float d2 = dx*dx + dy*dy;
            if (d2 <= 12.25f)
                atomicAdd(ws + WS_MAP + b*65536 + Y*256 + X, P.w * __expf(-d2 * P.z));
        }
    }
}

// Per-b max via 16 blocks/b + uint atomicMax (valid for non-negative floats).
__global__ __launch_bounds__(256) void k_max(float* __restrict__ ws) {
    int g = blockIdx.x;                     // 128
    int b = g >> 4;
    const float4* m = (const float4*)(ws + WS_MAP + b*65536 + (g & 15)*4096);
    float mx = 0.f;
    #pragma unroll
    for (int k = 0; k < 4; ++k) {
        float4 v = m[k*256 + threadIdx.x];
        mx = fmaxf(mx, fmaxf(fmaxf(v.x, v.y), fmaxf(v.z, v.w)));
    }
    #pragma unroll
    for (int s2 = 32; s2 >= 1; s2 >>= 1) mx = fmaxf(mx, __shfl_xor(mx, s2, 64));
    __shared__ float red[4];
    if ((threadIdx.x & 63) == 0) red[threadIdx.x >> 6] = mx;
    __syncthreads();
    if (threadIdx.x == 0) {
        mx = fmaxf(fmaxf(red[0], red[1]), fmaxf(red[2], red[3]));
        atomicMax((unsigned int*)(ws + WS_MAX + b), __float_as_uint(mx));
    }
}

// rot90 + normalize via padded LDS tile: out[b,r,c] = raw[b, c, 255-r] / max.
__global__ __launch_bounds__(256) void k_final(const float* __restrict__ ws,
                                               float* __restrict__ out) {
    __shared__ float tile[32][33];
    int g  = blockIdx.x;                    // 512 = 8 b x 64 tiles
    int b  = g >> 6;
    int t6 = g & 63;
    int r0 = (t6 >> 3) * 32;
    int c0 = (t6 & 7) * 32;
    int ic0 = 224 - r0;                     // input col start = 255 - r0 - 31
    int j  = threadIdx.x & 31;
    int i0 = threadIdx.x >> 5;
    const float* m = ws + WS_MAP + b*65536;
    #pragma unroll
    for (int p = 0; p < 4; ++p) {
        int i = i0 + p*8;
        tile[i][j] = m[(c0+i)*256 + ic0 + j];   // coalesced load
    }
    __syncthreads();
    float inv = 1.f/(ws[WS_MAX + b] + 1e-8f);
    #pragma unroll
    for (int p = 0; p < 4; ++p) {
        int k = i0 + p*8;
        out[b*65536 + (r0+k)*256 + c0 + j] = tile[j][31-k] * inv;  // coalesced store
    }
}

extern "C" void kernel_launch(void* const* d_in, const int* in_sizes, int n_in,
                              void* d_out, int out_size, void* d_ws, size_t ws_size,
                              hipStream_t stream) {
    const float* params    = (const float*)d_in[0];
    const float* logits    = (const float*)d_in[1];
    const float* v1_pos    = (const float*)d_in[2];
    const float* v1_prf    = (const float*)d_in[3];
    const float* start_loc = (const float*)d_in[4];
    const float* lut       = (const float*)d_in[5];
    const float* agrid     = (const float*)d_in[6];
    const float* bgrid     = (const float*)d_in[7];
    const float* tmpl      = (const float*)d_in[8];
    float* ws  = (float*)d_ws;
    float* out = (float*)d_out;

    k_weights<<<1024, 256, 0, stream>>>(params, start_loc, lut, agrid, bgrid,
                                        v1_pos, v1_prf, tmpl, ws);
    k_prender<<<128,  256, 0, stream>>>(logits, ws);
    k_max    <<<128,  256, 0, stream>>>(ws);
    k_final  <<<512,  256, 0, stream>>>(ws, out);
}

// Round 8
// 102.839 us; speedup vs baseline: 1.4800x; 1.2201x over previous
//
#include <hip/hip_runtime.h>
#include <math.h>

// ---- workspace layout (float offsets); we use ~9.5 MB ----
#define WS_MAP    0              // 524288: B x 256 x 256 raw map
#define WS_CNT    524416         // 320 ints: per (src-block 40, batch 8) survivor counts
#define WS_EPOS   524736         // 8192 x float4 (px,py,pz, C|P|^2)
#define WS_CPOS   557504         // 8 x 10240 x float4 compacted (-2Cx,-2Cy,-2Cz, C|q|^2)
#define WS_CPRF   885184         // 8 x 10240 x float2 compacted (pol, ecc)
#define WS_PART   1049024        // 8 x 40 x 1024 x float4 partials (5.2 MB)
#define WS_MAX    2359744        // 8 per-b max

#define NB 8
#define NN 1000
#define NV 10000
#define NSEG 40                  // segments = k_cull source blocks
#define SEGCAP 256               // <= 256 survivors per (block,batch), provably
#define NEB 1024                 // padded electrodes per batch

// Cull + pack: 40 blocks x 256. Per-block redundant batch setup; analytic AABB
// of each batch's electrode box (halfext_i = sum_j |R_ij|*h_j, h=(1.8,1.8,sh/2));
// point survives batch b iff dist^2(point, AABB_b) <= 90 (excluded points give
// wv <= e^-20 = 2e-9; 1e4 of them <= 2e-5 on sw -> map error <= ~1e-4 << 2e-2).
// Ballot-compacted into per-(block,batch) segments (no init race, cap exact).
// Also precomputes electrode positions (EPOS), zeroes the map, inits WS_MAX.
__global__ __launch_bounds__(256) void k_cull(const float* __restrict__ params,
                                              const float* __restrict__ start_loc,
                                              const float* __restrict__ lut,
                                              const float* __restrict__ agrid,
                                              const float* __restrict__ bgrid,
                                              const float* __restrict__ v1_pos,
                                              const float* __restrict__ v1_prf,
                                              const float* __restrict__ tmpl,
                                              float* __restrict__ ws) {
    __shared__ float sst[NB*16];   // R[9], center[3], shank, halfext[3]
    __shared__ int   lcnt[NB];
    int g = blockIdx.x, t = threadIdx.x;
    int v = g*256 + t;
    // zero map: 131072 float4 over 10240 threads
    float4* mp = (float4*)(ws + WS_MAP);
    #pragma unroll
    for (int k = 0; k < 13; ++k) {
        int idx = k*10240 + v;
        if (idx < 131072) mp[idx] = make_float4(0.f,0.f,0.f,0.f);
    }
    if (g == 0 && t < NB) ws[WS_MAX + t] = 0.f;
    if (t < NB) lcnt[t] = 0;
    if (t < NB) {    // per-batch setup (redundant per block)
        int b = t;
        float alpha = params[b*4+0], beta = params[b*4+1];
        float off   = params[b*4+2], shank = params[b*4+3];
        const float D2R = 0.017453292519943295f;
        float a = alpha*D2R, bb = beta*D2R;
        float ca = cosf(a), sa = sinf(a), cb = cosf(bb), sb = sinf(bb);
        float r00=cb,     r01=0.f, r02=sb;
        float r10=sa*sb,  r11=ca,  r12=-sa*cb;
        float r20=-ca*sb, r21=sa,  r22=ca*cb;
        float dx=-r02, dy=-r12, dz=-r22;
        float inv = rsqrtf(dx*dx+dy*dy+dz*dz);
        dx*=inv; dy*=inv; dz*=inv;
        float ag0=agrid[0], agN=agrid[36], bg0=bgrid[0], bgN=bgrid[25];
        float an = 2.f*(alpha-ag0)/(agN-ag0+1e-8f) - 1.f;
        float bn = 2.f*(beta -bg0)/(bgN-bg0+1e-8f) - 1.f;
        float ai = fminf(fmaxf((an+1.f)*0.5f*36.f, 0.f), 36.f);
        float bi = fminf(fmaxf((bn+1.f)*0.5f*25.f, 0.f), 25.f);
        int a0 = (int)floorf(ai); a0 = a0<0?0:(a0>36?36:a0);
        int b0 = (int)floorf(bi); b0 = b0<0?0:(b0>25?25:b0);
        int a1 = a0+1>36?36:a0+1;
        int b1 = b0+1>25?25:b0+1;
        float fa = ai - (float)a0, fb = bi - (float)b0;
        float v00=lut[a0*26+b0], v01=lut[a0*26+b1], v10=lut[a1*26+b0], v11=lut[a1*26+b1];
        float sd = v00*(1.f-fa)*(1.f-fb) + v01*(1.f-fa)*fb + v10*fa*(1.f-fb) + v11*fa*fb;
        sd = fmaxf(sd, 1.f);
        float pen = sd - shank*0.5f - off;
        float hs = shank*0.5f;
        sst[b*16+0]=r00; sst[b*16+1]=r01; sst[b*16+2]=r02;
        sst[b*16+3]=r10; sst[b*16+4]=r11; sst[b*16+5]=r12;
        sst[b*16+6]=r20; sst[b*16+7]=r21; sst[b*16+8]=r22;
        sst[b*16+9]  = start_loc[0] + dx*pen;
        sst[b*16+10] = start_loc[1] + dy*pen;
        sst[b*16+11] = start_loc[2] + dz*pen;
        sst[b*16+12] = shank;
        sst[b*16+13] = fabsf(r00)*1.8f + fabsf(r01)*1.8f + fabsf(r02)*hs;
        sst[b*16+14] = fabsf(r10)*1.8f + fabsf(r11)*1.8f + fabsf(r12)*hs;
        sst[b*16+15] = fabsf(r20)*1.8f + fabsf(r21)*1.8f + fabsf(r22)*hs;
    }
    __syncthreads();
    const float C = -0.32059889797532524f;   // -log2(e)/4.5
    // precompute electrode positions: e = v (0..8191)
    if (v < 8192) {
        float4* ep = (float4*)(ws + WS_EPOS);
        if (v < NB*NN) {
            int b = v/1000, n = v - b*1000;
            const float* st = sst + b*16;
            float gx = tmpl[n*3]-1.8f, gy = tmpl[n*3+1]-1.8f;
            float gz = (tmpl[n*3+2]-0.5f)*st[12];
            float px = st[0]*gx + st[1]*gy + st[2]*gz + st[9];
            float py = st[3]*gx + st[4]*gy + st[5]*gz + st[10];
            float pz = st[6]*gx + st[7]*gy + st[8]*gz + st[11];
            ep[v] = make_float4(px, py, pz, C*(px*px+py*py+pz*pz));
        } else {
            ep[v] = make_float4(0.f, 0.f, 0.f, -1e30f);
        }
    }
    // cull this thread's v1 point against each batch AABB (no early returns —
    // every thread must reach every __ballot)
    bool valid = v < NV;
    float x=0.f, y=0.f, z=0.f, pol=0.f, ecc=0.f;
    if (valid) {
        x = v1_pos[v*3]; y = v1_pos[v*3+1]; z = v1_pos[v*3+2];
        pol = v1_prf[v*3]; ecc = v1_prf[v*3+1];
    }
    float4 payload = make_float4(-2.f*C*x, -2.f*C*y, -2.f*C*z, C*(x*x+y*y+z*z));
    int lane = t & 63;
    float4* cpos = (float4*)(ws + WS_CPOS);
    float2* cprf = (float2*)(ws + WS_CPRF);
    #pragma unroll
    for (int b = 0; b < NB; ++b) {
        const float* st = sst + b*16;
        float dxc = fmaxf(fabsf(x - st[9])  - st[13], 0.f);
        float dyc = fmaxf(fabsf(y - st[10]) - st[14], 0.f);
        float dzc = fmaxf(fabsf(z - st[11]) - st[15], 0.f);
        bool pred = valid && (dxc*dxc + dyc*dyc + dzc*dzc <= 90.f);
        unsigned long long m = __ballot(pred);
        int base = 0;
        if (lane == 0) base = atomicAdd(&lcnt[b], (int)__popcll(m));
        base = __shfl(base, 0, 64);
        if (pred) {
            int my = base + (int)__popcll(m & ((1ull << lane) - 1ull));
            int slot = b*10240 + g*SEGCAP + my;      // my < 256 guaranteed
            cpos[slot] = payload;
            cprf[slot] = make_float2(pol, ecc);
        }
    }
    __syncthreads();
    if (t < NB) ((int*)(ws + WS_CNT))[g*NB + t] = lcnt[t];
}

// Soft-match over compacted survivors. 640 blocks = 8 b x 40 segments x 2 elec
// groups; 2 electrodes/thread. Segment (<=256 entries) staged in LDS; inner
// loop bound is the dynamic survivor count.
__global__ __launch_bounds__(256) void k_match(float* __restrict__ ws) {
    __shared__ float4 sq[SEGCAP];
    __shared__ float2 spe[SEGCAP];
    int g = blockIdx.x, t = threadIdx.x;
    int b = g / 80, r = g - b*80, q = r >> 1, eg = r & 1;
    int cq = ((const int*)(ws + WS_CNT))[q*NB + b];
    if (t < cq) {
        sq[t]  = ((const float4*)(ws + WS_CPOS))[b*10240 + q*SEGCAP + t];
        spe[t] = ((const float2*)(ws + WS_CPRF))[b*10240 + q*SEGCAP + t];
    }
    __syncthreads();
    const float4* ep = (const float4*)(ws + WS_EPOS);
    int n0 = eg*512 + t, n1 = n0 + 256;
    float4 P0 = (n0 < NN) ? ep[b*NN + n0] : make_float4(0.f,0.f,0.f,-1e30f);
    float4 P1 = (n1 < NN) ? ep[b*NN + n1] : make_float4(0.f,0.f,0.f,-1e30f);
    float sw0=0.f,sp0=0.f,se0=0.f, sw1=0.f,sp1=0.f,se1=0.f;
    #pragma unroll 2
    for (int i = 0; i < cq; ++i) {
        float4 qq = sq[i];
        float2 pe = spe[i];
        float a0 = fmaf(qq.x, P0.x, fmaf(qq.y, P0.y, fmaf(qq.z, P0.z, P0.w + qq.w)));
        float w0 = __builtin_amdgcn_exp2f(a0);
        sw0 += w0; sp0 = fmaf(w0, pe.x, sp0); se0 = fmaf(w0, pe.y, se0);
        float a1 = fmaf(qq.x, P1.x, fmaf(qq.y, P1.y, fmaf(qq.z, P1.z, P1.w + qq.w)));
        float w1 = __builtin_amdgcn_exp2f(a1);
        sw1 += w1; sp1 = fmaf(w1, pe.x, sp1); se1 = fmaf(w1, pe.y, se1);
    }
    float4* part = (float4*)(ws + WS_PART);
    int baseq = (b*NSEG + q)*NEB;
    part[baseq + n0] = make_float4(sw0, sp0, se0, 0.f);
    part[baseq + n1] = make_float4(sw1, sp1, se1, 0.f);
}

// Fused params+render: 128 blocks = 8 b x 16 tiles of 64 electrodes.
// Phase A: wave w sums segments q = w, w+4, ..., w+36 (coalesced, lane=elec).
// Phase B: wave 0 combines, computes render params. Phase C: each wave renders
// 16 electrodes' 8x8 windows (d2 <= 12.25; truncation ~5e-3 pre-norm, << 2e-2).
__global__ __launch_bounds__(256) void k_prender(const float* __restrict__ logits,
                                                 float* __restrict__ ws) {
    __shared__ float4 red[4][64];
    __shared__ float4 par[64];
    int g = blockIdx.x, t = threadIdx.x, lane = t & 63, w = t >> 6;
    int b = g >> 4, E0 = (g & 15) * 64;
    const float4* part = (const float4*)(ws + WS_PART);
    int el = E0 + lane;
    float sw = 0.f, sp = 0.f, se = 0.f;
    #pragma unroll
    for (int i = 0; i < 10; ++i) {
        float4 p = part[(b*NSEG + (w + i*4))*NEB + el];
        sw += p.x; sp += p.y; se += p.z;
    }
    red[w][lane] = make_float4(sw, sp, se, 0.f);
    __syncthreads();
    if (w == 0) {
        float4 a = red[0][lane], b4 = red[1][lane], c4 = red[2][lane], d4 = red[3][lane];
        sw = (a.x+b4.x) + (c4.x+d4.x);
        sp = (a.y+b4.y) + (c4.y+d4.y);
        se = (a.z+b4.z) + (c4.z+d4.z);
        float denom = sw + 1e-8f;
        float pol = sp/denom, eccv = se/denom;
        float validity = fminf(sw, 1.f);
        int n = E0 + lane;
        float lg = (n < NN) ? logits[b*NN + n] : 0.f;
        float prob = 1.f/(1.f + __expf(-lg));
        float wgt = (n < NN) ? prob * validity : 0.f;
        float ang = pol * 0.017453292519943295f;
        float m1 = 17.3f*(1.f/(eccv+0.75f) - 1.f/(eccv+120.f));
        float minv = 1.f/(fabsf(m1)+1e-8f);
        float sig  = 0.3849001794597506f * minv * 0.5f;   // sqrt(100/675)*m_inv/2
        const float scl = 256.f/90.f;
        float s = fmaxf(sig*scl, 1.f);                    // provably == 1.0 (ecc<=12)
        float invden = 1.f/(s*s + 1e-8f);
        par[lane] = make_float4(eccv*__cosf(ang)*scl + 128.f,
                                eccv*__sinf(ang)*scl + 128.f, invden, wgt);
    }
    __syncthreads();
    int ix = lane & 7, iy = lane >> 3;       // 8x8 window, one pass of 64 lanes
    for (int k = 0; k < 16; ++k) {
        int el2 = k*4 + w;
        float4 P = par[el2];
        if (P.w <= 0.f) continue;            // wave-uniform
        int fx = (int)floorf(P.x), fy = (int)floorf(P.y);
        int X = fx - 3 + ix, Y = fy - 3 + iy;
        if (X >= 0 && X < 256 && Y >= 0 && Y < 256) {
            float dx = (float)X - P.x, dy = (float)Y - P.y;
            float d2 = dx*dx + dy*dy;
            if (d2 <= 12.25f)
                atomicAdd(ws + WS_MAP + b*65536 + Y*256 + X, P.w * __expf(-d2 * P.z));
        }
    }
}

// Per-b max via 16 blocks/b + uint atomicMax (valid for non-negative floats).
__global__ __launch_bounds__(256) void k_max(float* __restrict__ ws) {
    int g = blockIdx.x;                     // 128
    int b = g >> 4;
    const float4* m = (const float4*)(ws + WS_MAP + b*65536 + (g & 15)*4096);
    float mx = 0.f;
    #pragma unroll
    for (int k = 0; k < 4; ++k) {
        float4 v = m[k*256 + threadIdx.x];
        mx = fmaxf(mx, fmaxf(fmaxf(v.x, v.y), fmaxf(v.z, v.w)));
    }
    #pragma unroll
    for (int s2 = 32; s2 >= 1; s2 >>= 1) mx = fmaxf(mx, __shfl_xor(mx, s2, 64));
    __shared__ float red[4];
    if ((threadIdx.x & 63) == 0) red[threadIdx.x >> 6] = mx;
    __syncthreads();
    if (threadIdx.x == 0) {
        mx = fmaxf(fmaxf(red[0], red[1]), fmaxf(red[2], red[3]));
        atomicMax((unsigned int*)(ws + WS_MAX + b), __float_as_uint(mx));
    }
}

// rot90 + normalize via padded LDS tile: out[b,r,c] = raw[b, c, 255-r] / max.
__global__ __launch_bounds__(256) void k_final(const float* __restrict__ ws,
                                               float* __restrict__ out) {
    __shared__ float tile[32][33];
    int g  = blockIdx.x;                    // 512 = 8 b x 64 tiles
    int b  = g >> 6;
    int t6 = g & 63;
    int r0 = (t6 >> 3) * 32;
    int c0 = (t6 & 7) * 32;
    int ic0 = 224 - r0;                     // input col start = 255 - r0 - 31
    int j  = threadIdx.x & 31;
    int i0 = threadIdx.x >> 5;
    const float* m = ws + WS_MAP + b*65536;
    #pragma unroll
    for (int p = 0; p < 4; ++p) {
        int i = i0 + p*8;
        tile[i][j] = m[(c0+i)*256 + ic0 + j];   // coalesced load
    }
    __syncthreads();
    float inv = 1.f/(ws[WS_MAX + b] + 1e-8f);
    #pragma unroll
    for (int p = 0; p < 4; ++p) {
        int k = i0 + p*8;
        out[b*65536 + (r0+k)*256 + c0 + j] = tile[j][31-k] * inv;  // coalesced store
    }
}

extern "C" void kernel_launch(void* const* d_in, const int* in_sizes, int n_in,
                              void* d_out, int out_size, void* d_ws, size_t ws_size,
                              hipStream_t stream) {
    const float* params    = (const float*)d_in[0];
    const float* logits    = (const float*)d_in[1];
    const float* v1_pos    = (const float*)d_in[2];
    const float* v1_prf    = (const float*)d_in[3];
    const float* start_loc = (const float*)d_in[4];
    const float* lut       = (const float*)d_in[5];
    const float* agrid     = (const float*)d_in[6];
    const float* bgrid     = (const float*)d_in[7];
    const float* tmpl      = (const float*)d_in[8];
    float* ws  = (float*)d_ws;
    float* out = (float*)d_out;

    k_cull   <<<40,  256, 0, stream>>>(params, start_loc, lut, agrid, bgrid,
                                       v1_pos, v1_prf, tmpl, ws);
    k_match  <<<640, 256, 0, stream>>>(ws);
    k_prender<<<128, 256, 0, stream>>>(logits, ws);
    k_max    <<<128, 256, 0, stream>>>(ws);
    k_final  <<<512, 256, 0, stream>>>(ws, out);
}

// Round 9
// 101.655 us; speedup vs baseline: 1.4972x; 1.0116x over previous
//
#include <hip/hip_runtime.h>
#include <math.h>

// ---- workspace layout (float offsets); we use ~6.5 MB ----
#define WS_MAP    0              // 524288: B x 256 x 256 raw map
#define WS_CNT    524416         // 320 ints: per (src-block 40, batch 8) survivor counts
#define WS_EPOS   524736         // 8192 x float4 (px,py,pz, C|P|^2)
#define WS_CPOS   557504         // 8 x 10240 x float4 compacted (-2Cx,-2Cy,-2Cz, C|q|^2)
#define WS_CPRF   885184         // 8 x 10240 x float2 compacted (pol, ecc)
#define WS_PART   1049024        // 8 x 20 x 1024 x float4 partials (2.6 MB)
#define WS_MAX    1704384        // 8 per-b max

#define NB 8
#define NN 1000
#define NV 10000
#define NSEG 40                  // cull source blocks (segments)
#define NSEG2 20                 // match super-segments (2 source segs each)
#define SEGCAP 256               // <= 256 survivors per (block,batch), structural
#define NEB 1024                 // padded electrodes per batch

// Cull + pack: 40 blocks x 256. Per-block redundant batch setup; analytic AABB
// of each batch's electrode box (halfext_i = sum_j |R_ij|*h_j, h=(1.8,1.8,sh/2));
// point survives batch b iff dist^2(point, AABB_b) <= 90 (excluded points give
// wv <= e^-20 = 2e-9; 1e4 of them <= 2e-5 on sw -> map error ~1e-4 << 2e-2).
// Ballot-compacted into per-(block,batch) segments. Also precomputes electrode
// positions (EPOS), zeroes the map, inits WS_MAX.
__global__ __launch_bounds__(256) void k_cull(const float* __restrict__ params,
                                              const float* __restrict__ start_loc,
                                              const float* __restrict__ lut,
                                              const float* __restrict__ agrid,
                                              const float* __restrict__ bgrid,
                                              const float* __restrict__ v1_pos,
                                              const float* __restrict__ v1_prf,
                                              const float* __restrict__ tmpl,
                                              float* __restrict__ ws) {
    __shared__ float sst[NB*16];   // R[9], center[3], shank, halfext[3]
    __shared__ int   lcnt[NB];
    int g = blockIdx.x, t = threadIdx.x;
    int v = g*256 + t;
    // zero map: 131072 float4 over 10240 threads
    float4* mp = (float4*)(ws + WS_MAP);
    #pragma unroll
    for (int k = 0; k < 13; ++k) {
        int idx = k*10240 + v;
        if (idx < 131072) mp[idx] = make_float4(0.f,0.f,0.f,0.f);
    }
    if (g == 0 && t < NB) ws[WS_MAX + t] = 0.f;
    if (t < NB) lcnt[t] = 0;
    if (t < NB) {    // per-batch setup (redundant per block)
        int b = t;
        float alpha = params[b*4+0], beta = params[b*4+1];
        float off   = params[b*4+2], shank = params[b*4+3];
        const float D2R = 0.017453292519943295f;
        float a = alpha*D2R, bb = beta*D2R;
        float ca = cosf(a), sa = sinf(a), cb = cosf(bb), sb = sinf(bb);
        float r00=cb,     r01=0.f, r02=sb;
        float r10=sa*sb,  r11=ca,  r12=-sa*cb;
        float r20=-ca*sb, r21=sa,  r22=ca*cb;
        float dx=-r02, dy=-r12, dz=-r22;
        float inv = rsqrtf(dx*dx+dy*dy+dz*dz);
        dx*=inv; dy*=inv; dz*=inv;
        float ag0=agrid[0], agN=agrid[36], bg0=bgrid[0], bgN=bgrid[25];
        float an = 2.f*(alpha-ag0)/(agN-ag0+1e-8f) - 1.f;
        float bn = 2.f*(beta -bg0)/(bgN-bg0+1e-8f) - 1.f;
        float ai = fminf(fmaxf((an+1.f)*0.5f*36.f, 0.f), 36.f);
        float bi = fminf(fmaxf((bn+1.f)*0.5f*25.f, 0.f), 25.f);
        int a0 = (int)floorf(ai); a0 = a0<0?0:(a0>36?36:a0);
        int b0 = (int)floorf(bi); b0 = b0<0?0:(b0>25?25:b0);
        int a1 = a0+1>36?36:a0+1;
        int b1 = b0+1>25?25:b0+1;
        float fa = ai - (float)a0, fb = bi - (float)b0;
        float v00=lut[a0*26+b0], v01=lut[a0*26+b1], v10=lut[a1*26+b0], v11=lut[a1*26+b1];
        float sd = v00*(1.f-fa)*(1.f-fb) + v01*(1.f-fa)*fb + v10*fa*(1.f-fb) + v11*fa*fb;
        sd = fmaxf(sd, 1.f);
        float pen = sd - shank*0.5f - off;
        float hs = shank*0.5f;
        sst[b*16+0]=r00; sst[b*16+1]=r01; sst[b*16+2]=r02;
        sst[b*16+3]=r10; sst[b*16+4]=r11; sst[b*16+5]=r12;
        sst[b*16+6]=r20; sst[b*16+7]=r21; sst[b*16+8]=r22;
        sst[b*16+9]  = start_loc[0] + dx*pen;
        sst[b*16+10] = start_loc[1] + dy*pen;
        sst[b*16+11] = start_loc[2] + dz*pen;
        sst[b*16+12] = shank;
        sst[b*16+13] = fabsf(r00)*1.8f + fabsf(r01)*1.8f + fabsf(r02)*hs;
        sst[b*16+14] = fabsf(r10)*1.8f + fabsf(r11)*1.8f + fabsf(r12)*hs;
        sst[b*16+15] = fabsf(r20)*1.8f + fabsf(r21)*1.8f + fabsf(r22)*hs;
    }
    __syncthreads();
    const float C = -0.32059889797532524f;   // -log2(e)/4.5
    // precompute electrode positions: e = v (0..8191)
    if (v < 8192) {
        float4* ep = (float4*)(ws + WS_EPOS);
        if (v < NB*NN) {
            int b = v/1000, n = v - b*1000;
            const float* st = sst + b*16;
            float gx = tmpl[n*3]-1.8f, gy = tmpl[n*3+1]-1.8f;
            float gz = (tmpl[n*3+2]-0.5f)*st[12];
            float px = st[0]*gx + st[1]*gy + st[2]*gz + st[9];
            float py = st[3]*gx + st[4]*gy + st[5]*gz + st[10];
            float pz = st[6]*gx + st[7]*gy + st[8]*gz + st[11];
            ep[v] = make_float4(px, py, pz, C*(px*px+py*py+pz*pz));
        } else {
            ep[v] = make_float4(0.f, 0.f, 0.f, -1e30f);
        }
    }
    // cull this thread's v1 point against each batch AABB (no early returns —
    // every thread must reach every __ballot)
    bool valid = v < NV;
    float x=0.f, y=0.f, z=0.f, pol=0.f, ecc=0.f;
    if (valid) {
        x = v1_pos[v*3]; y = v1_pos[v*3+1]; z = v1_pos[v*3+2];
        pol = v1_prf[v*3]; ecc = v1_prf[v*3+1];
    }
    float4 payload = make_float4(-2.f*C*x, -2.f*C*y, -2.f*C*z, C*(x*x+y*y+z*z));
    int lane = t & 63;
    float4* cpos = (float4*)(ws + WS_CPOS);
    float2* cprf = (float2*)(ws + WS_CPRF);
    #pragma unroll
    for (int b = 0; b < NB; ++b) {
        const float* st = sst + b*16;
        float dxc = fmaxf(fabsf(x - st[9])  - st[13], 0.f);
        float dyc = fmaxf(fabsf(y - st[10]) - st[14], 0.f);
        float dzc = fmaxf(fabsf(z - st[11]) - st[15], 0.f);
        bool pred = valid && (dxc*dxc + dyc*dyc + dzc*dzc <= 90.f);
        unsigned long long m = __ballot(pred);
        int base = 0;
        if (lane == 0) base = atomicAdd(&lcnt[b], (int)__popcll(m));
        base = __shfl(base, 0, 64);
        if (pred) {
            int my = base + (int)__popcll(m & ((1ull << lane) - 1ull));
            int slot = b*10240 + g*SEGCAP + my;      // my < 256 structural
            cpos[slot] = payload;
            cprf[slot] = make_float2(pol, ecc);
        }
    }
    __syncthreads();
    if (t < NB) ((int*)(ws + WS_CNT))[g*NB + t] = lcnt[t];
}

// Soft-match over compacted survivors. 320 blocks = 8 b x 20 super-segments
// (2 source segments each, <=512 survivors staged) x 2 elec groups; 2
// electrodes/thread. Inner loop bound = dynamic survivor count (~80 avg).
__global__ __launch_bounds__(256) void k_match(float* __restrict__ ws) {
    __shared__ float4 sq[2*SEGCAP];
    __shared__ float2 spe[2*SEGCAP];
    int g = blockIdx.x, t = threadIdx.x;
    int b = g / 40, r = g - b*40, qp = r >> 1, eg = r & 1;
    int q0 = qp*2, q1 = qp*2 + 1;
    const int* cnt = (const int*)(ws + WS_CNT);
    int c0 = cnt[q0*NB + b], c1 = cnt[q1*NB + b];
    const float4* cpos = (const float4*)(ws + WS_CPOS);
    const float2* cprf = (const float2*)(ws + WS_CPRF);
    if (t < c0) {
        sq[t]  = cpos[b*10240 + q0*SEGCAP + t];
        spe[t] = cprf[b*10240 + q0*SEGCAP + t];
    }
    if (t < c1) {
        sq[c0 + t]  = cpos[b*10240 + q1*SEGCAP + t];
        spe[c0 + t] = cprf[b*10240 + q1*SEGCAP + t];
    }
    __syncthreads();
    int cq = c0 + c1;
    const float4* ep = (const float4*)(ws + WS_EPOS);
    int n0 = eg*512 + t, n1 = n0 + 256;
    float4 P0 = (n0 < NN) ? ep[b*NN + n0] : make_float4(0.f,0.f,0.f,-1e30f);
    float4 P1 = (n1 < NN) ? ep[b*NN + n1] : make_float4(0.f,0.f,0.f,-1e30f);
    float sw0=0.f,sp0=0.f,se0=0.f, sw1=0.f,sp1=0.f,se1=0.f;
    #pragma unroll 2
    for (int i = 0; i < cq; ++i) {
        float4 qq = sq[i];
        float2 pe = spe[i];
        float a0 = fmaf(qq.x, P0.x, fmaf(qq.y, P0.y, fmaf(qq.z, P0.z, P0.w + qq.w)));
        float w0 = __builtin_amdgcn_exp2f(a0);
        sw0 += w0; sp0 = fmaf(w0, pe.x, sp0); se0 = fmaf(w0, pe.y, se0);
        float a1 = fmaf(qq.x, P1.x, fmaf(qq.y, P1.y, fmaf(qq.z, P1.z, P1.w + qq.w)));
        float w1 = __builtin_amdgcn_exp2f(a1);
        sw1 += w1; sp1 = fmaf(w1, pe.x, sp1); se1 = fmaf(w1, pe.y, se1);
    }
    float4* part = (float4*)(ws + WS_PART);
    int baseq = (b*NSEG2 + qp)*NEB;
    part[baseq + n0] = make_float4(sw0, sp0, se0, 0.f);
    part[baseq + n1] = make_float4(sw1, sp1, se1, 0.f);
}

// Fused params+render+max: 128 blocks = 8 b x 16 tiles of 64 electrodes.
// Phase A: wave w sums super-segments w, w+4, ..., w+16 (coalesced, lane=elec).
// Phase B: wave 0 combines, computes render params. Phase C: each wave renders
// 16 electrodes' 8x8 windows (d2 <= 12.25; truncation ~5e-3 pre-norm << 2e-2).
// Max trick (exact): atomicAdd returns old; the LAST add to a pixel observes
// old+val == final value, and every observation is <= its pixel's final ->
// max over all observed (old+val), 0-init, equals the true map max.
__global__ __launch_bounds__(256) void k_prender(const float* __restrict__ logits,
                                                 float* __restrict__ ws) {
    __shared__ float4 red[4][64];
    __shared__ float4 par[64];
    __shared__ float  mred[4];
    int g = blockIdx.x, t = threadIdx.x, lane = t & 63, w = t >> 6;
    int b = g >> 4, E0 = (g & 15) * 64;
    const float4* part = (const float4*)(ws + WS_PART);
    int el = E0 + lane;
    float sw = 0.f, sp = 0.f, se = 0.f;
    #pragma unroll
    for (int i = 0; i < 5; ++i) {
        float4 p = part[(b*NSEG2 + (w + i*4))*NEB + el];
        sw += p.x; sp += p.y; se += p.z;
    }
    red[w][lane] = make_float4(sw, sp, se, 0.f);
    __syncthreads();
    if (w == 0) {
        float4 a = red[0][lane], b4 = red[1][lane], c4 = red[2][lane], d4 = red[3][lane];
        sw = (a.x+b4.x) + (c4.x+d4.x);
        sp = (a.y+b4.y) + (c4.y+d4.y);
        se = (a.z+b4.z) + (c4.z+d4.z);
        float denom = sw + 1e-8f;
        float pol = sp/denom, eccv = se/denom;
        float validity = fminf(sw, 1.f);
        int n = E0 + lane;
        float lg = (n < NN) ? logits[b*NN + n] : 0.f;
        float prob = 1.f/(1.f + __expf(-lg));
        float wgt = (n < NN) ? prob * validity : 0.f;
        float ang = pol * 0.017453292519943295f;
        float m1 = 17.3f*(1.f/(eccv+0.75f) - 1.f/(eccv+120.f));
        float minv = 1.f/(fabsf(m1)+1e-8f);
        float sig  = 0.3849001794597506f * minv * 0.5f;   // sqrt(100/675)*m_inv/2
        const float scl = 256.f/90.f;
        float s = fmaxf(sig*scl, 1.f);                    // provably == 1.0 (ecc<=12)
        float invden = 1.f/(s*s + 1e-8f);
        par[lane] = make_float4(eccv*__cosf(ang)*scl + 128.f,
                                eccv*__sinf(ang)*scl + 128.f, invden, wgt);
    }
    __syncthreads();
    int ix = lane & 7, iy = lane >> 3;       // 8x8 window, one pass of 64 lanes
    float mx = 0.f;
    for (int k = 0; k < 16; ++k) {
        int el2 = k*4 + w;
        float4 P = par[el2];
        if (P.w <= 0.f) continue;            // wave-uniform
        int fx = (int)floorf(P.x), fy = (int)floorf(P.y);
        int X = fx - 3 + ix, Y = fy - 3 + iy;
        if (X >= 0 && X < 256 && Y >= 0 && Y < 256) {
            float dx = (float)X - P.x, dy = (float)Y - P.y;
            float d2 = dx*dx + dy*dy;
            if (d2 <= 12.25f) {
                float val = P.w * __expf(-d2 * P.z);
                float old = atomicAdd(ws + WS_MAP + b*65536 + Y*256 + X, val);
                mx = fmaxf(mx, old + val);
            }
        }
    }
    // block max -> per-b atomicMax (uint compare valid: all values >= 0)
    #pragma unroll
    for (int s2 = 32; s2 >= 1; s2 >>= 1) mx = fmaxf(mx, __shfl_xor(mx, s2, 64));
    if (lane == 0) mred[w] = mx;
    __syncthreads();
    if (t == 0) {
        mx = fmaxf(fmaxf(mred[0], mred[1]), fmaxf(mred[2], mred[3]));
        atomicMax((unsigned int*)(ws + WS_MAX + b), __float_as_uint(mx));
    }
}

// rot90 + normalize via padded LDS tile: out[b,r,c] = raw[b, c, 255-r] / max.
__global__ __launch_bounds__(256) void k_final(const float* __restrict__ ws,
                                               float* __restrict__ out) {
    __shared__ float tile[32][33];
    int g  = blockIdx.x;                    // 512 = 8 b x 64 tiles
    int b  = g >> 6;
    int t6 = g & 63;
    int r0 = (t6 >> 3) * 32;
    int c0 = (t6 & 7) * 32;
    int ic0 = 224 - r0;                     // input col start = 255 - r0 - 31
    int j  = threadIdx.x & 31;
    int i0 = threadIdx.x >> 5;
    const float* m = ws + WS_MAP + b*65536;
    #pragma unroll
    for (int p = 0; p < 4; ++p) {
        int i = i0 + p*8;
        tile[i][j] = m[(c0+i)*256 + ic0 + j];   // coalesced load
    }
    __syncthreads();
    float inv = 1.f/(ws[WS_MAX + b] + 1e-8f);
    #pragma unroll
    for (int p = 0; p < 4; ++p) {
        int k = i0 + p*8;
        out[b*65536 + (r0+k)*256 + c0 + j] = tile[j][31-k] * inv;  // coalesced store
    }
}

extern "C" void kernel_launch(void* const* d_in, const int* in_sizes, int n_in,
                              void* d_out, int out_size, void* d_ws, size_t ws_size,
                              hipStream_t stream) {
    const float* params    = (const float*)d_in[0];
    const float* logits    = (const float*)d_in[1];
    const float* v1_pos    = (const float*)d_in[2];
    const float* v1_prf    = (const float*)d_in[3];
    const float* start_loc = (const float*)d_in[4];
    const float* lut       = (const float*)d_in[5];
    const float* agrid     = (const float*)d_in[6];
    const float* bgrid     = (const float*)d_in[7];
    const float* tmpl      = (const float*)d_in[8];
    float* ws  = (float*)d_ws;
    float* out = (float*)d_out;

    k_cull   <<<40,  256, 0, stream>>>(params, start_loc, lut, agrid, bgrid,
                                       v1_pos, v1_prf, tmpl, ws);
    k_match  <<<320, 256, 0, stream>>>(ws);
    k_prender<<<128, 256, 0, stream>>>(logits, ws);
    k_final  <<<512, 256, 0, stream>>>(ws, out);
}